// Round 2
// baseline (59.685 us; speedup 1.0000x reference)
//
#include <hip/hip_runtime.h>
#include <stdint.h>

#define HW 3136
#define NB 8

typedef unsigned short ushort_t;
typedef __attribute__((ext_vector_type(8))) short bf16x8;
typedef __attribute__((ext_vector_type(4))) float f32x4;

__device__ __forceinline__ ushort_t f2bf(float v) {
  uint32_t u = __builtin_bit_cast(uint32_t, v);
  u += 0x7FFF + ((u >> 16) & 1);   // round-to-nearest-even
  return (ushort_t)(u >> 16);
}
__device__ __forceinline__ float bf2f(ushort_t h) {
  uint32_t u = ((uint32_t)h) << 16;
  return __builtin_bit_cast(float, u);
}

__device__ __forceinline__ void gload16(const void* g, void* l) {
  __builtin_amdgcn_global_load_lds(
      (const __attribute__((address_space(1))) void*)g,
      (__attribute__((address_space(3))) void*)l, 16, 0, 0);
}

// ---------------- Kernel 1: L2-normalize over C=64, split fp32 -> bf16 hi/lo,
// store (n,p,c) row-major (128B rows) with 16B-slot XOR swizzle keyed on p&7.
__global__ __launch_bounds__(256) void norm_split_kernel(
    const float* __restrict__ q, const float* __restrict__ k,
    ushort_t* __restrict__ qh, ushort_t* __restrict__ ql,
    ushort_t* __restrict__ kh, ushort_t* __restrict__ kl) {
  const float* src = blockIdx.y ? k : q;
  ushort_t* dh = blockIdx.y ? kh : qh;
  ushort_t* dl = blockIdx.y ? kl : ql;
  const int n = blockIdx.x / 49, pb = blockIdx.x % 49;
  const int p0 = pb * 64;
  __shared__ float tile[64][65];
  __shared__ float psum[4][64];
  __shared__ float invs[64];
  const int tid = threadIdx.x, px = tid & 63, grp = tid >> 6;

  for (int c = grp; c < 64; c += 4)
    tile[c][px] = src[(size_t)(n * 64 + c) * HW + p0 + px];
  __syncthreads();

  float s = 0.f;
  #pragma unroll
  for (int e = 0; e < 16; ++e) { float v = tile[grp * 16 + e][px]; s += v * v; }
  psum[grp][px] = s;
  __syncthreads();
  if (tid < 64) {
    float t = psum[0][tid] + psum[1][tid] + psum[2][tid] + psum[3][tid];
    invs[tid] = 1.0f / fmaxf(sqrtf(t), 1e-8f);
  }
  __syncthreads();

  const int c = tid & 63;
  for (int pl = grp; pl < 64; pl += 4) {
    float v = tile[c][pl] * invs[pl];
    ushort_t h = f2bf(v);
    ushort_t l = f2bf(v - bf2f(h));
    const int p = p0 + pl;
    const size_t row = (size_t)n * HW + p;
    const int off = (((c >> 3) ^ (p & 7)) << 3) | (c & 7);  // swizzled elem-in-row
    dh[row * 64 + off] = h;
    dl[row * 64 + off] = l;
  }
}

// ---------------- Kernel 2: masked pair-sum GEMM.
// Block: 128 q-rows (i-tile), loops 5 j-chunks of 128. 4 waves as 2x2, each
// wave owns 64x64 output. logit = qh*kh + qh*kl + ql*kh via mfma 16x16x32 bf16.
#define SQH 0
#define SQL 16384
#define SKH 32768
#define SKL 49152
#define SCQX 65536
#define SCQY 66048
#define SCKX 66560
#define SCKY 67072
#define SMEM_BYTES 67584

__global__ __launch_bounds__(256, 2) void pair_sum_kernel(
    const ushort_t* __restrict__ qh, const ushort_t* __restrict__ ql,
    const ushort_t* __restrict__ kh, const ushort_t* __restrict__ kl,
    const float* __restrict__ cqx, const float* __restrict__ cqy,
    const float* __restrict__ ckx, const float* __restrict__ cky,
    float* __restrict__ partial) {
  __shared__ __align__(16) char smem[SMEM_BYTES];
  const int bid = blockIdx.x;
  const int n = bid / 125;
  const int rem = bid % 125;
  const int i0 = (rem / 5) * 128;
  const int js = rem % 5;
  const int tid = threadIdx.x, lane = tid & 63, wid = tid >> 6;
  const int wr = wid >> 1, wc = wid & 1;
  const size_t base = (size_t)n * HW * 64;  // ushort elems per batch

  // stage Q tiles (hi & lo), 16KB each, linear LDS dest (data pre-swizzled)
  #pragma unroll
  for (int pass = 0; pass < 4; ++pass) {
    const int idx = pass * 256 + tid;      // 16B unit, 0..1023
    int grow = i0 + (idx >> 3);
    if (grow > HW - 1) grow = HW - 1;      // clamp tail (masked via centers)
    const int unit = idx & 7;
    gload16(qh + base + (size_t)grow * 64 + unit * 8, smem + SQH + idx * 16);
    gload16(ql + base + (size_t)grow * 64 + unit * 8, smem + SQL + idx * 16);
  }
  if (tid < 128) {
    const int gi = i0 + tid;
    // Tail sentinel +1e9 (k-side uses -1e9) so tail-tail pairs still mask out.
    float x = 1e9f, y = 1e9f;
    if (gi < HW) { x = cqx[n * HW + gi]; y = cqy[n * HW + gi]; }
    ((float*)(smem + SCQX))[tid] = x;
    ((float*)(smem + SCQY))[tid] = y;
  }

  float num = 0.f, den = 0.f;

  for (int jc = js * 5; jc < js * 5 + 5; ++jc) {
    const int j0 = jc * 128;
    __syncthreads();  // prev epilogue done with sK/centers; drains Q stage on iter 0

    #pragma unroll
    for (int pass = 0; pass < 4; ++pass) {
      const int idx = pass * 256 + tid;
      int grow = j0 + (idx >> 3);
      if (grow > HW - 1) grow = HW - 1;
      const int unit = idx & 7;
      gload16(kh + base + (size_t)grow * 64 + unit * 8, smem + SKH + idx * 16);
      gload16(kl + base + (size_t)grow * 64 + unit * 8, smem + SKL + idx * 16);
    }
    if (tid < 128) {
      const int gj = j0 + tid;
      float x = -1e9f, y = -1e9f;   // asymmetric sentinel vs q-side +1e9
      if (gj < HW) { x = ckx[n * HW + gj]; y = cky[n * HW + gj]; }
      ((float*)(smem + SCKX))[tid] = x;
      ((float*)(smem + SCKY))[tid] = y;
    }
    __syncthreads();

    f32x4 acc[4][4];
    #pragma unroll
    for (int a = 0; a < 4; ++a)
      #pragma unroll
      for (int b = 0; b < 4; ++b) acc[a][b] = (f32x4){0.f, 0.f, 0.f, 0.f};

    #pragma unroll
    for (int kk = 0; kk < 2; ++kk) {
      bf16x8 Ah[4], Al[4], Bh[4], Bl[4];
      #pragma unroll
      for (int t = 0; t < 4; ++t) {
        const int row = wr * 64 + t * 16 + (lane & 15);
        const int aoff = row * 128 + (((kk * 4 + (lane >> 4)) ^ (row & 7)) << 4);
        Ah[t] = *(const bf16x8*)(smem + SQH + aoff);
        Al[t] = *(const bf16x8*)(smem + SQL + aoff);
        const int jrow = wc * 64 + t * 16 + (lane & 15);
        const int boff = jrow * 128 + (((kk * 4 + (lane >> 4)) ^ (jrow & 7)) << 4);
        Bh[t] = *(const bf16x8*)(smem + SKH + boff);
        Bl[t] = *(const bf16x8*)(smem + SKL + boff);
      }
      #pragma unroll
      for (int tr = 0; tr < 4; ++tr)
        #pragma unroll
        for (int tc = 0; tc < 4; ++tc) {
          acc[tr][tc] = __builtin_amdgcn_mfma_f32_16x16x32_bf16(Ah[tr], Bh[tc], acc[tr][tc], 0, 0, 0);
          acc[tr][tc] = __builtin_amdgcn_mfma_f32_16x16x32_bf16(Ah[tr], Bl[tc], acc[tr][tc], 0, 0, 0);
          acc[tr][tc] = __builtin_amdgcn_mfma_f32_16x16x32_bf16(Al[tr], Bh[tc], acc[tr][tc], 0, 0, 0);
        }
    }

    // epilogue: mask + accumulate. C/D: col = lane&15, row = (lane>>4)*4 + reg.
    const float* scqx = (const float*)(smem + SCQX);
    const float* scqy = (const float*)(smem + SCQY);
    const float* sckx = (const float*)(smem + SCKX);
    const float* scky = (const float*)(smem + SCKY);
    #pragma unroll
    for (int tr = 0; tr < 4; ++tr) {
      #pragma unroll
      for (int r = 0; r < 4; ++r) {
        const int il = wr * 64 + tr * 16 + (lane >> 4) * 4 + r;
        const float qx = scqx[il], qy = scqy[il];
        #pragma unroll
        for (int tc = 0; tc < 4; ++tc) {
          const int jl = wc * 64 + tc * 16 + (lane & 15);
          const float dx = qx - sckx[jl];
          const float dy = qy - scky[jl];
          const float d2 = dx * dx + dy * dy;
          const bool m = d2 < 0.48999998f;  // 0.7f*0.7f
          num += m ? acc[tr][tc][r] : 0.f;
          den += m ? 1.f : 0.f;
        }
      }
    }
  }

  // deterministic block reduce
  __syncthreads();
  float* red = (float*)smem;
  red[tid] = num;
  red[256 + tid] = den;
  __syncthreads();
  #pragma unroll
  for (int s = 128; s > 0; s >>= 1) {
    if (tid < s) { red[tid] += red[tid + s]; red[256 + tid] += red[256 + tid + s]; }
    __syncthreads();
  }
  if (tid == 0) { partial[bid * 2] = red[0]; partial[bid * 2 + 1] = red[256]; }
}

// ---------------- Kernel 3: final reduce over 125 partials per batch.
__global__ __launch_bounds__(256) void finalize_kernel(const float* __restrict__ partial,
                                                       float* __restrict__ out) {
  __shared__ float rat[8];
  const int tid = threadIdx.x;
  const int n = tid >> 5, s = tid & 31;
  float num = 0.f, den = 0.f;
  for (int p = s; p < 125; p += 32) {
    num += partial[(n * 125 + p) * 2];
    den += partial[(n * 125 + p) * 2 + 1];
  }
  #pragma unroll
  for (int off = 16; off > 0; off >>= 1) {
    num += __shfl_down(num, off, 32);
    den += __shfl_down(den, off, 32);
  }
  if (s == 0) rat[n] = num / (den + 1e-6f);
  __syncthreads();
  if (tid == 0) {
    float t = 0.f;
    #pragma unroll
    for (int i = 0; i < 8; ++i) t += rat[i];
    out[0] = -0.25f * t;  // -2 * mean over 8 batches
  }
}

extern "C" void kernel_launch(void* const* d_in, const int* in_sizes, int n_in,
                              void* d_out, int out_size, void* d_ws, size_t ws_size,
                              hipStream_t stream) {
  const float* q   = (const float*)d_in[0];
  const float* k   = (const float*)d_in[1];
  const float* cqx = (const float*)d_in[2];
  const float* cqy = (const float*)d_in[3];
  const float* ckx = (const float*)d_in[4];
  const float* cky = (const float*)d_in[5];

  const size_t ARR = (size_t)NB * HW * 64;  // 1,605,632 elems
  ushort_t* qh = (ushort_t*)d_ws;
  ushort_t* ql = qh + ARR;
  ushort_t* kh = ql + ARR;
  ushort_t* kl = kh + ARR;
  float* partial = (float*)((char*)d_ws + ARR * 4 * sizeof(ushort_t));

  norm_split_kernel<<<dim3(392, 2), 256, 0, stream>>>(q, k, qh, ql, kh, kl);
  pair_sum_kernel<<<1000, 256, 0, stream>>>(qh, ql, kh, kl, cqx, cqy, ckx, cky, partial);
  finalize_kernel<<<1, 256, 0, stream>>>(partial, (float*)d_out);
}

// Round 5
// 48.059 us; speedup vs baseline: 1.2419x; 1.2419x over previous
//
#include <hip/hip_runtime.h>
#include <stdint.h>

#define HW 3136
#define NB 8

typedef unsigned short ushort_t;
typedef __attribute__((ext_vector_type(8))) _Float16 f16x8;
typedef __attribute__((ext_vector_type(4))) float f32x4;

__device__ __forceinline__ void gload16(const void* g, void* l) {
  __builtin_amdgcn_global_load_lds(
      (const __attribute__((address_space(1))) void*)g,
      (__attribute__((address_space(3))) void*)l, 16, 0, 0);
}

// ---------------- Kernel 1: L2-normalize over C=64, cast fp32 -> fp16,
// store (n,p,c) row-major (128B rows) with 16B-slot XOR swizzle keyed on p&7.
__global__ __launch_bounds__(256) void norm_cast_kernel(
    const float* __restrict__ q, const float* __restrict__ k,
    ushort_t* __restrict__ qh, ushort_t* __restrict__ kh) {
  const float* src = blockIdx.y ? k : q;
  ushort_t* dh = blockIdx.y ? kh : qh;
  const int n = blockIdx.x / 49, pb = blockIdx.x % 49;
  const int p0 = pb * 64;
  __shared__ float tile[64][65];
  __shared__ float psum[4][64];
  __shared__ float invs[64];
  const int tid = threadIdx.x, px = tid & 63, grp = tid >> 6;

  for (int c = grp; c < 64; c += 4)
    tile[c][px] = src[(size_t)(n * 64 + c) * HW + p0 + px];
  __syncthreads();

  float s = 0.f;
  #pragma unroll
  for (int e = 0; e < 16; ++e) { float v = tile[grp * 16 + e][px]; s += v * v; }
  psum[grp][px] = s;
  __syncthreads();
  if (tid < 64) {
    float t = psum[0][tid] + psum[1][tid] + psum[2][tid] + psum[3][tid];
    invs[tid] = 1.0f / fmaxf(sqrtf(t), 1e-8f);
  }
  __syncthreads();

  const int c = tid & 63;
  for (int pl = grp; pl < 64; pl += 4) {
    float v = tile[c][pl] * invs[pl];
    _Float16 h = (_Float16)v;
    const int p = p0 + pl;
    const size_t row = (size_t)n * HW + p;
    const int off = (((c >> 3) ^ (p & 7)) << 3) | (c & 7);  // swizzled elem-in-row
    dh[row * 64 + off] = __builtin_bit_cast(ushort_t, h);
  }
}

// ---------------- Kernel 2: masked pair-sum GEMM, single fp16 pass.
// Block: 128 q-rows, loops 5 j-chunks of 128. 4 waves as 2x2, each wave owns
// 64x64 output. mfma_f32_16x16x32_f16.
#define SQH 0
#define SKH 16384
#define SCQX 32768
#define SCQY 33280
#define SCKX 33792
#define SCKY 34304
#define SMEM_BYTES 34816

__global__ __launch_bounds__(256, 4) void pair_sum_kernel(
    const ushort_t* __restrict__ qh, const ushort_t* __restrict__ kh,
    const float* __restrict__ cqx, const float* __restrict__ cqy,
    const float* __restrict__ ckx, const float* __restrict__ cky,
    float* __restrict__ partial) {
  __shared__ __align__(16) char smem[SMEM_BYTES];
  const int bid = blockIdx.x;
  const int n = bid / 125;
  const int rem = bid % 125;
  const int i0 = (rem / 5) * 128;
  const int js = rem % 5;
  const int tid = threadIdx.x, lane = tid & 63, wid = tid >> 6;
  const int wr = wid >> 1, wc = wid & 1;
  const size_t base = (size_t)n * HW * 64;  // ushort elems per batch

  // stage Q tile (16KB), linear LDS dest (data pre-swizzled in global)
  #pragma unroll
  for (int pass = 0; pass < 4; ++pass) {
    const int idx = pass * 256 + tid;      // 16B unit, 0..1023
    int grow = i0 + (idx >> 3);
    if (grow > HW - 1) grow = HW - 1;      // clamp tail (masked via centers)
    const int unit = idx & 7;
    gload16(qh + base + (size_t)grow * 64 + unit * 8, smem + SQH + idx * 16);
  }
  if (tid < 128) {
    const int gi = i0 + tid;
    // Tail sentinel +1e9 (k-side uses -1e9) so tail-tail pairs also mask out.
    float x = 1e9f, y = 1e9f;
    if (gi < HW) { x = cqx[n * HW + gi]; y = cqy[n * HW + gi]; }
    ((float*)(smem + SCQX))[tid] = x;
    ((float*)(smem + SCQY))[tid] = y;
  }

  float num = 0.f;
  unsigned int dcnt = 0;

  for (int jc = js * 5; jc < js * 5 + 5; ++jc) {
    const int j0 = jc * 128;
    __syncthreads();  // prev chunk done with sK/centers; drains Q stage on iter 0

    #pragma unroll
    for (int pass = 0; pass < 4; ++pass) {
      const int idx = pass * 256 + tid;
      int grow = j0 + (idx >> 3);
      if (grow > HW - 1) grow = HW - 1;
      const int unit = idx & 7;
      gload16(kh + base + (size_t)grow * 64 + unit * 8, smem + SKH + idx * 16);
    }
    if (tid < 128) {
      const int gj = j0 + tid;
      float x = -1e9f, y = -1e9f;   // asymmetric sentinel vs q-side +1e9
      if (gj < HW) { x = ckx[n * HW + gj]; y = cky[n * HW + gj]; }
      ((float*)(smem + SCKX))[tid] = x;
      ((float*)(smem + SCKY))[tid] = y;
    }
    __syncthreads();

    f32x4 acc[4][4];
    #pragma unroll
    for (int a = 0; a < 4; ++a)
      #pragma unroll
      for (int b = 0; b < 4; ++b) acc[a][b] = (f32x4){0.f, 0.f, 0.f, 0.f};

    #pragma unroll
    for (int kk = 0; kk < 2; ++kk) {
      f16x8 Ah[4], Bh[4];
      #pragma unroll
      for (int t = 0; t < 4; ++t) {
        const int row = wr * 64 + t * 16 + (lane & 15);
        const int aoff = row * 128 + (((kk * 4 + (lane >> 4)) ^ (row & 7)) << 4);
        Ah[t] = *(const f16x8*)(smem + SQH + aoff);
        const int jrow = wc * 64 + t * 16 + (lane & 15);
        const int boff = jrow * 128 + (((kk * 4 + (lane >> 4)) ^ (jrow & 7)) << 4);
        Bh[t] = *(const f16x8*)(smem + SKH + boff);
      }
      #pragma unroll
      for (int tr = 0; tr < 4; ++tr)
        #pragma unroll
        for (int tc = 0; tc < 4; ++tc)
          acc[tr][tc] = __builtin_amdgcn_mfma_f32_16x16x32_f16(Ah[tr], Bh[tc], acc[tr][tc], 0, 0, 0);
    }

    // epilogue: mask + accumulate. C/D: col = lane&15, row = (lane>>4)*4 + reg.
    const float* scqx = (const float*)(smem + SCQX);
    const float* scqy = (const float*)(smem + SCQY);
    const float* sckx = (const float*)(smem + SCKX);
    const float* scky = (const float*)(smem + SCKY);
    float kcx[4], kcy[4];
    #pragma unroll
    for (int tc = 0; tc < 4; ++tc) {
      const int jl = wc * 64 + tc * 16 + (lane & 15);
      kcx[tc] = sckx[jl];
      kcy[tc] = scky[jl];
    }
    #pragma unroll
    for (int tr = 0; tr < 4; ++tr) {
      #pragma unroll
      for (int r = 0; r < 4; ++r) {
        const int il = wr * 64 + tr * 16 + (lane >> 4) * 4 + r;
        const float qx = scqx[il], qy = scqy[il];
        #pragma unroll
        for (int tc = 0; tc < 4; ++tc) {
          const float dx = qx - kcx[tc];
          const float dy = qy - kcy[tc];
          float d2 = dx * dx;
          d2 = fmaf(dy, dy, d2);
          const bool m = d2 < 0.48999998f;  // 0.7f*0.7f
          num += m ? acc[tr][tc][r] : 0.f;
          // den via wave-uniform ballot popcount (scalar pipe)
          dcnt += (unsigned int)__popcll(__ballot(m));
        }
      }
    }
  }

  // deterministic block reduce (num per-lane; dcnt is wave-uniform: lane0 only)
  __syncthreads();
  float* red = (float*)smem;
  red[tid] = num;
  red[256 + tid] = (lane == 0) ? (float)dcnt : 0.f;
  __syncthreads();
  #pragma unroll
  for (int s = 128; s > 0; s >>= 1) {
    if (tid < s) { red[tid] += red[tid + s]; red[256 + tid] += red[256 + tid + s]; }
    __syncthreads();
  }
  if (tid == 0) { partial[bid * 2] = red[0]; partial[bid * 2 + 1] = red[256]; }
}

// ---------------- Kernel 3: final reduce over 125 partials per batch.
__global__ __launch_bounds__(256) void finalize_kernel(const float* __restrict__ partial,
                                                       float* __restrict__ out) {
  __shared__ float rat[8];
  const int tid = threadIdx.x;
  const int n = tid >> 5, s = tid & 31;
  float num = 0.f, den = 0.f;
  for (int p = s; p < 125; p += 32) {
    num += partial[(n * 125 + p) * 2];
    den += partial[(n * 125 + p) * 2 + 1];
  }
  #pragma unroll
  for (int off = 16; off > 0; off >>= 1) {
    num += __shfl_down(num, off, 32);
    den += __shfl_down(den, off, 32);
  }
  if (s == 0) rat[n] = num / (den + 1e-6f);
  __syncthreads();
  if (tid == 0) {
    float t = 0.f;
    #pragma unroll
    for (int i = 0; i < 8; ++i) t += rat[i];
    out[0] = -0.25f * t;  // -2 * mean over 8 batches
  }
}

extern "C" void kernel_launch(void* const* d_in, const int* in_sizes, int n_in,
                              void* d_out, int out_size, void* d_ws, size_t ws_size,
                              hipStream_t stream) {
  const float* q   = (const float*)d_in[0];
  const float* k   = (const float*)d_in[1];
  const float* cqx = (const float*)d_in[2];
  const float* cqy = (const float*)d_in[3];
  const float* ckx = (const float*)d_in[4];
  const float* cky = (const float*)d_in[5];

  const size_t ARR = (size_t)NB * HW * 64;  // 1,605,632 elems
  ushort_t* qh = (ushort_t*)d_ws;
  ushort_t* kh = qh + ARR;
  float* partial = (float*)((char*)d_ws + ARR * 2 * sizeof(ushort_t));

  norm_cast_kernel<<<dim3(392, 2), 256, 0, stream>>>(q, k, qh, kh);
  pair_sum_kernel<<<1000, 256, 0, stream>>>(qh, kh, cqx, cqy, ckx, cky, partial);
  finalize_kernel<<<1, 256, 0, stream>>>(partial, (float*)d_out);
}

// Round 6
// 43.548 us; speedup vs baseline: 1.3706x; 1.1036x over previous
//
#include <hip/hip_runtime.h>
#include <stdint.h>

#define HW  3136
#define HWP 3200
#define NB  8

typedef unsigned short ushort_t;
typedef __attribute__((ext_vector_type(8))) _Float16 f16x8;
typedef __attribute__((ext_vector_type(4))) float f32x4;

__device__ __forceinline__ void gload16(const void* g, void* l) {
  __builtin_amdgcn_global_load_lds(
      (const __attribute__((address_space(1))) void*)g,
      (__attribute__((address_space(3))) void*)l, 16, 0, 0);
}

// ---------------- Kernel 1: L2-normalize over C=64, cast fp32 -> fp16,
// store (n,p,c) rows (128B) with 16B-slot XOR swizzle keyed on p&7, into
// HWP=3200-row padded arrays. pb==49 writes zero rows + sentinel centers.
// Also copies centers into padded center arrays.
__global__ __launch_bounds__(256) void norm_cast_kernel(
    const float* __restrict__ q, const float* __restrict__ k,
    const float* __restrict__ cqx, const float* __restrict__ cqy,
    const float* __restrict__ ckx, const float* __restrict__ cky,
    ushort_t* __restrict__ qh, ushort_t* __restrict__ kh,
    float* __restrict__ cqxp, float* __restrict__ cqyp,
    float* __restrict__ ckxp, float* __restrict__ ckyp) {
  const int isK = blockIdx.y;
  const float* src = isK ? k : q;
  ushort_t* dh = isK ? kh : qh;
  float* cxp = isK ? ckxp : cqxp;
  float* cyp = isK ? ckyp : cqyp;
  const float* cx = isK ? ckx : cqx;
  const float* cy = isK ? cky : cqy;
  const float sent = isK ? -1e9f : 1e9f;
  const int n = blockIdx.x / 50, pb = blockIdx.x % 50;
  const int tid = threadIdx.x;

  if (pb == 49) {  // padding rows 3136..3199
    uint4 z = make_uint4(0u, 0u, 0u, 0u);
    uint4* dst = (uint4*)(dh + ((size_t)n * HWP + HW) * 64);
    #pragma unroll
    for (int u = tid; u < 512; u += 256) dst[u] = z;   // 8KB of zeros
    if (tid < 64) {
      cxp[(size_t)n * HWP + HW + tid] = sent;
      cyp[(size_t)n * HWP + HW + tid] = sent;
    }
    return;
  }

  const int p0 = pb * 64;
  __shared__ float tile[64][65];
  __shared__ float psum[4][64];
  __shared__ float invs[64];
  const int px = tid & 63, grp = tid >> 6;

  for (int c = grp; c < 64; c += 4)
    tile[c][px] = src[(size_t)(n * 64 + c) * HW + p0 + px];
  if (tid < 64) {  // copy centers into padded arrays
    cxp[(size_t)n * HWP + p0 + tid] = cx[(size_t)n * HW + p0 + tid];
    cyp[(size_t)n * HWP + p0 + tid] = cy[(size_t)n * HW + p0 + tid];
  }
  __syncthreads();

  float s = 0.f;
  #pragma unroll
  for (int e = 0; e < 16; ++e) { float v = tile[grp * 16 + e][px]; s += v * v; }
  psum[grp][px] = s;
  __syncthreads();
  if (tid < 64) {
    float t = psum[0][tid] + psum[1][tid] + psum[2][tid] + psum[3][tid];
    invs[tid] = 1.0f / fmaxf(sqrtf(t), 1e-8f);
  }
  __syncthreads();

  const int c = tid & 63;
  for (int pl = grp; pl < 64; pl += 4) {
    float v = tile[c][pl] * invs[pl];
    _Float16 h = (_Float16)v;
    const int p = p0 + pl;
    const size_t row = (size_t)n * HWP + p;
    const int off = (((c >> 3) ^ (p & 7)) << 3) | (c & 7);  // swizzled elem-in-row
    dh[row * 64 + off] = __builtin_bit_cast(ushort_t, h);
  }
}

// ---------------- Kernel 2: masked pair-sum GEMM, 2-phase pipelined.
// Block: 128 q-rows, 10 j-chunks of 64 rows (double-buffered K in LDS).
// 4 waves as 2x2; each wave owns 64x32 of each chunk. mfma_f32_16x16x32_f16.
#define SQ    0       // 16384 B: Q tile 128 rows x 128B
#define SK0   16384   // 8192 B: K chunk buf 0
#define SK1   24576   // 8192 B: K chunk buf 1
#define SKC0  32768   // 512 B: kcx[64], kcy[64] buf 0
#define SKC1  33280   // 512 B: buf 1
#define SQC   33792   // 1024 B: qcx[128], qcy[128]
#define SMEM_BYTES 34816

__global__ __launch_bounds__(256, 4) void pair_sum_kernel(
    const ushort_t* __restrict__ qh, const ushort_t* __restrict__ kh,
    const float* __restrict__ cqxp, const float* __restrict__ cqyp,
    const float* __restrict__ ckxp, const float* __restrict__ ckyp,
    float* __restrict__ partial) {
  __shared__ __align__(16) char smem[SMEM_BYTES];
  const int bid = blockIdx.x;
  const int n = bid / 125;
  const int rem = bid % 125;
  const int i0 = (rem / 5) * 128;
  const int js = rem % 5;
  const int tid = threadIdx.x, lane = tid & 63, wid = tid >> 6;
  const int wr = wid >> 1, wc = wid & 1;
  const size_t base = (size_t)n * HWP * 64;
  const size_t cbase = (size_t)n * HWP;

  // ---- prologue: stage Q, K chunk 0, k-centers 0, q-centers
  #pragma unroll
  for (int pass = 0; pass < 4; ++pass) {
    const int idx = pass * 256 + tid;
    gload16(qh + base + (size_t)(i0 + (idx >> 3)) * 64 + (idx & 7) * 8,
            smem + SQ + idx * 16);
  }
  const int j00 = js * 10 * 64;
  #pragma unroll
  for (int pass = 0; pass < 2; ++pass) {
    const int idx = pass * 256 + tid;
    gload16(kh + base + (size_t)(j00 + (idx >> 3)) * 64 + (idx & 7) * 8,
            smem + SK0 + idx * 16);
  }
  if (tid < 32) {
    const float* src = (lane < 16) ? (ckxp + cbase + j00 + lane * 4)
                                   : (ckyp + cbase + j00 + (lane - 16) * 4);
    gload16(src, smem + SKC0 + lane * 16);
  }
  if (tid < 64) {
    const float* src = (lane < 32) ? (cqxp + cbase + i0 + lane * 4)
                                   : (cqyp + cbase + i0 + (lane - 32) * 4);
    gload16(src, smem + SQC + lane * 16);
  }
  __syncthreads();

  // hoist q-centers to registers (reused across all 10 chunks)
  float qcx[4][4], qcy[4][4];
  {
    const float* sqc = (const float*)(smem + SQC);
    #pragma unroll
    for (int tr = 0; tr < 4; ++tr)
      #pragma unroll
      for (int r = 0; r < 4; ++r) {
        const int il = wr * 64 + tr * 16 + (lane >> 4) * 4 + r;
        qcx[tr][r] = sqc[il];
        qcy[tr][r] = sqc[128 + il];
      }
  }

  float num = 0.f;
  unsigned int dcnt = 0;

  for (int jt = 0; jt < 10; ++jt) {
    const int b = jt & 1;
    // ---- issue next-chunk stage first (T3 recipe)
    if (jt < 9) {
      const int j1 = (js * 10 + jt + 1) * 64;
      char* dk = smem + SK0 + (b ^ 1) * 8192;
      #pragma unroll
      for (int pass = 0; pass < 2; ++pass) {
        const int idx = pass * 256 + tid;
        gload16(kh + base + (size_t)(j1 + (idx >> 3)) * 64 + (idx & 7) * 8,
                dk + idx * 16);
      }
      if (tid < 32) {
        const float* src = (lane < 16) ? (ckxp + cbase + j1 + lane * 4)
                                       : (ckyp + cbase + j1 + (lane - 16) * 4);
        gload16(src, smem + SKC0 + (b ^ 1) * 512 + lane * 16);
      }
    }

    // ---- compute chunk jt from buf b
    f32x4 acc[4][2];
    #pragma unroll
    for (int a = 0; a < 4; ++a)
      #pragma unroll
      for (int c2 = 0; c2 < 2; ++c2) acc[a][c2] = (f32x4){0.f, 0.f, 0.f, 0.f};

    const char* sk = smem + SK0 + b * 8192;
    #pragma unroll
    for (int kk = 0; kk < 2; ++kk) {
      f16x8 Ah[4], Bh[2];
      #pragma unroll
      for (int t = 0; t < 4; ++t) {
        const int row = wr * 64 + t * 16 + (lane & 15);
        const int aoff = row * 128 + (((kk * 4 + (lane >> 4)) ^ (row & 7)) << 4);
        Ah[t] = *(const f16x8*)(smem + SQ + aoff);
      }
      #pragma unroll
      for (int t = 0; t < 2; ++t) {
        const int jr = wc * 32 + t * 16 + (lane & 15);
        const int boff = jr * 128 + (((kk * 4 + (lane >> 4)) ^ (jr & 7)) << 4);
        Bh[t] = *(const f16x8*)(sk + boff);
      }
      #pragma unroll
      for (int tr = 0; tr < 4; ++tr)
        #pragma unroll
        for (int tc = 0; tc < 2; ++tc)
          acc[tr][tc] = __builtin_amdgcn_mfma_f32_16x16x32_f16(Ah[tr], Bh[tc], acc[tr][tc], 0, 0, 0);
    }

    // ---- epilogue: mask + accumulate. C/D: col=lane&15, row=(lane>>4)*4+reg.
    const float* skc = (const float*)(smem + SKC0 + b * 512);
    float kx[2], ky[2];
    #pragma unroll
    for (int tc = 0; tc < 2; ++tc) {
      const int jl = wc * 32 + tc * 16 + (lane & 15);
      kx[tc] = skc[jl];
      ky[tc] = skc[64 + jl];
    }
    #pragma unroll
    for (int tr = 0; tr < 4; ++tr) {
      #pragma unroll
      for (int r = 0; r < 4; ++r) {
        const float qx = qcx[tr][r], qy = qcy[tr][r];
        #pragma unroll
        for (int tc = 0; tc < 2; ++tc) {
          const float dx = qx - kx[tc];
          const float dy = qy - ky[tc];
          float d2 = dx * dx;
          d2 = fmaf(dy, dy, d2);
          const bool m = d2 < 0.48999998f;  // 0.7^2
          num += m ? acc[tr][tc][r] : 0.f;
          dcnt += (unsigned int)__popcll(__ballot(m));  // scalar pipe
        }
      }
    }

    __syncthreads();  // drains vmcnt(0): next chunk staged; buf b free to overwrite
  }

  // ---- deterministic block reduce (num per-lane; dcnt wave-uniform: lane0)
  float* red = (float*)smem;
  red[tid] = num;
  red[256 + tid] = (lane == 0) ? (float)dcnt : 0.f;
  __syncthreads();
  #pragma unroll
  for (int s = 128; s > 0; s >>= 1) {
    if (tid < s) { red[tid] += red[tid + s]; red[256 + tid] += red[256 + tid + s]; }
    __syncthreads();
  }
  if (tid == 0) { partial[bid * 2] = red[0]; partial[bid * 2 + 1] = red[256]; }
}

// ---------------- Kernel 3: final reduce over 125 partials per batch.
__global__ __launch_bounds__(256) void finalize_kernel(const float* __restrict__ partial,
                                                       float* __restrict__ out) {
  __shared__ float rat[8];
  const int tid = threadIdx.x;
  const int n = tid >> 5, s = tid & 31;
  float num = 0.f, den = 0.f;
  for (int p = s; p < 125; p += 32) {
    num += partial[(n * 125 + p) * 2];
    den += partial[(n * 125 + p) * 2 + 1];
  }
  #pragma unroll
  for (int off = 16; off > 0; off >>= 1) {
    num += __shfl_down(num, off, 32);
    den += __shfl_down(den, off, 32);
  }
  if (s == 0) rat[n] = num / (den + 1e-6f);
  __syncthreads();
  if (tid == 0) {
    float t = 0.f;
    #pragma unroll
    for (int i = 0; i < 8; ++i) t += rat[i];
    out[0] = -0.25f * t;  // -2 * mean over 8 batches
  }
}

extern "C" void kernel_launch(void* const* d_in, const int* in_sizes, int n_in,
                              void* d_out, int out_size, void* d_ws, size_t ws_size,
                              hipStream_t stream) {
  const float* q   = (const float*)d_in[0];
  const float* k   = (const float*)d_in[1];
  const float* cqx = (const float*)d_in[2];
  const float* cqy = (const float*)d_in[3];
  const float* ckx = (const float*)d_in[4];
  const float* cky = (const float*)d_in[5];

  const size_t ARR = (size_t)NB * HWP * 64;  // padded feature rows
  ushort_t* qh = (ushort_t*)d_ws;
  ushort_t* kh = qh + ARR;
  float* cqxp = (float*)(kh + ARR);
  float* cqyp = cqxp + (size_t)NB * HWP;
  float* ckxp = cqyp + (size_t)NB * HWP;
  float* ckyp = ckxp + (size_t)NB * HWP;
  float* partial = ckyp + (size_t)NB * HWP;

  norm_cast_kernel<<<dim3(400, 2), 256, 0, stream>>>(
      q, k, cqx, cqy, ckx, cky, qh, kh, cqxp, cqyp, ckxp, ckyp);
  pair_sum_kernel<<<1000, 256, 0, stream>>>(
      qh, kh, cqxp, cqyp, ckxp, ckyp, partial);
  finalize_kernel<<<1, 256, 0, stream>>>(partial, (float*)d_out);
}